// Round 1
// baseline (74.197 us; speedup 1.0000x reference)
//
#include <hip/hip_runtime.h>

#define HGT 128
#define WID 128
#define HW  (HGT * WID)          // 16384
#define CCH 64
#define NHEADS 4
#define NA 36                    // HEADS * KK
#define NB 4

// workspace layout (floats)
#define WR_FG_OFF 0              // 64*36
#define WR_BG_OFF 2304           // 64*36
#define BIAS_OFF  4608           // 36
#define V_OFF     4672           // B*64*HW = 4194304
#define ATTN_OFF  (4672 + 4194304)  // B*36*HW = 2359296

// ---------------------------------------------------------------------------
// Kernel 0: reduce attention weights over the summed i-axis.
// Wr[c][h*9+j] = sum_i W[c][h*81 + i*9 + j];  bias_attn[hj] = sum_i (bfg+bbg)
// ---------------------------------------------------------------------------
__global__ void reduce_weights_kernel(const float* __restrict__ Wfg,
                                      const float* __restrict__ bfg,
                                      const float* __restrict__ Wbg,
                                      const float* __restrict__ bbg,
                                      float* __restrict__ ws) {
    int idx = blockIdx.x * 256 + threadIdx.x;
    if (idx < 2 * 2304) {
        int which = idx / 2304;
        int r = idx % 2304;
        int c = r / 36, hj = r % 36;
        int h = hj / 9, j = hj % 9;
        const float* W = which ? Wbg : Wfg;
        float s = 0.f;
        #pragma unroll
        for (int i = 0; i < 9; i++) s += W[c * 324 + h * 81 + i * 9 + j];
        ws[(which ? WR_BG_OFF : WR_FG_OFF) + r] = s;
    } else if (idx < 2 * 2304 + 36) {
        int hj = idx - 4608;
        int h = hj / 9, j = hj % 9;
        float s = 0.f;
        #pragma unroll
        for (int i = 0; i < 9; i++)
            s += bfg[h * 81 + i * 9 + j] + bbg[h * 81 + i * 9 + j];
        ws[BIAS_OFF + hj] = s;
    }
}

// ---------------------------------------------------------------------------
// Kernel 1: per-pixel projections.
//   v[b][o][l]    = sum_c x[b][c][l]  * Wv[c][o]  + bv[o]        (64 outs)
//   attn[b][hj][l]= sum_c fg[b][c][l] * Wrfg[c][hj]
//                 + sum_c bg[b][c][l] * Wrbg[c][hj] + ba[hj]     (36 outs)
// One thread per pixel; weights broadcast from LDS; inputs in registers.
// ---------------------------------------------------------------------------
__global__ __launch_bounds__(256) void proj_kernel(
        const float* __restrict__ x, const float* __restrict__ fg,
        const float* __restrict__ bg, const float* __restrict__ Wv,
        const float* __restrict__ bv, const float* __restrict__ ws,
        float* __restrict__ v_out, float* __restrict__ attn_out) {
    __shared__ float sWv[64 * 64];
    __shared__ float sWfg[64 * 36];
    __shared__ float sWbg[64 * 36];
    __shared__ float sbv[64];
    __shared__ float sba[36];

    int tid = threadIdx.x;
    for (int i = tid; i < 64 * 64; i += 256) sWv[i] = Wv[i];
    for (int i = tid; i < 64 * 36; i += 256) {
        sWfg[i] = ws[WR_FG_OFF + i];
        sWbg[i] = ws[WR_BG_OFF + i];
    }
    if (tid < 64) sbv[tid] = bv[tid];
    if (tid < 36) sba[tid] = ws[BIAS_OFF + tid];
    __syncthreads();

    int p = blockIdx.x * 256 + tid;
    int b = p >> 14;           // / HW
    int l = p & (HW - 1);

    float xr[64];

    // ---- v = x @ Wv + bv ----
    const float* xb = x + (size_t)b * CCH * HW + l;
    #pragma unroll
    for (int c = 0; c < 64; c++) xr[c] = xb[(size_t)c * HW];

    #pragma unroll
    for (int oc = 0; oc < 4; oc++) {
        float acc[16];
        #pragma unroll
        for (int o = 0; o < 16; o++) acc[o] = sbv[oc * 16 + o];
        #pragma unroll
        for (int c = 0; c < 64; c++) {
            float xv = xr[c];
            #pragma unroll
            for (int o = 0; o < 16; o++)
                acc[o] += xv * sWv[c * 64 + oc * 16 + o];
        }
        #pragma unroll
        for (int o = 0; o < 16; o++)
            v_out[((size_t)b * 64 + oc * 16 + o) * HW + l] = acc[o];
    }

    // ---- attn = fg @ Wrfg + bg @ Wrbg + ba ----
    float acc[36];
    #pragma unroll
    for (int o = 0; o < 36; o++) acc[o] = sba[o];

    const float* fb = fg + (size_t)b * CCH * HW + l;
    #pragma unroll
    for (int c = 0; c < 64; c++) xr[c] = fb[(size_t)c * HW];
    #pragma unroll
    for (int c = 0; c < 64; c++) {
        float xv = xr[c];
        #pragma unroll
        for (int o = 0; o < 36; o++) acc[o] += xv * sWfg[c * 36 + o];
    }

    const float* gb = bg + (size_t)b * CCH * HW + l;
    #pragma unroll
    for (int c = 0; c < 64; c++) xr[c] = gb[(size_t)c * HW];
    #pragma unroll
    for (int c = 0; c < 64; c++) {
        float xv = xr[c];
        #pragma unroll
        for (int o = 0; o < 36; o++) acc[o] += xv * sWbg[c * 36 + o];
    }

    #pragma unroll
    for (int o = 0; o < 36; o++)
        attn_out[((size_t)b * 36 + o) * HW + l] = acc[o];
}

// ---------------------------------------------------------------------------
// Kernel 2: aggregation.
//   out[b][c][l] = sum_j attn[b][h(c)*9+j][l] * v[b][c][nbr_j(l)]
// One thread per (pixel, head); 16 channels per thread.
// Zero-padding handled by zeroing the weight and clamping the offset.
// ---------------------------------------------------------------------------
__global__ __launch_bounds__(256) void agg_kernel(
        const float* __restrict__ v, const float* __restrict__ attn,
        float* __restrict__ out) {
    int idx = blockIdx.x * 256 + threadIdx.x;     // B*4*HW threads
    int l = idx & (HW - 1);
    int rest = idx >> 14;
    int b = rest >> 2;
    int h = rest & 3;
    int y = l >> 7, xx = l & 127;

    const float* ab = attn + ((size_t)b * 36 + h * 9) * HW + l;
    float w[9];
    int off[9];
    #pragma unroll
    for (int j = 0; j < 9; j++) {
        w[j] = ab[(size_t)j * HW];
        int dy = j / 3 - 1, dx = j % 3 - 1;
        int yy = y + dy, xc = xx + dx;
        bool valid = (yy >= 0) && (yy < HGT) && (xc >= 0) && (xc < WID);
        off[j] = valid ? (yy * WID + xc) : l;
        if (!valid) w[j] = 0.f;
    }

    const float* vb = v + ((size_t)b * 64 + h * 16) * HW;
    float* ob = out + ((size_t)b * 64 + h * 16) * HW + l;
    #pragma unroll 4
    for (int c2 = 0; c2 < 16; c2++) {
        const float* vc = vb + (size_t)c2 * HW;
        float acc = 0.f;
        #pragma unroll
        for (int j = 0; j < 9; j++) acc += w[j] * vc[off[j]];
        ob[(size_t)c2 * HW] = acc;
    }
}

extern "C" void kernel_launch(void* const* d_in, const int* in_sizes, int n_in,
                              void* d_out, int out_size, void* d_ws, size_t ws_size,
                              hipStream_t stream) {
    const float* x   = (const float*)d_in[0];
    const float* fg  = (const float*)d_in[1];
    const float* bg  = (const float*)d_in[2];
    const float* Wv  = (const float*)d_in[3];
    const float* bv  = (const float*)d_in[4];
    const float* Wfg = (const float*)d_in[5];
    const float* bfg = (const float*)d_in[6];
    const float* Wbg = (const float*)d_in[7];
    const float* bbg = (const float*)d_in[8];

    float* ws  = (float*)d_ws;
    float* out = (float*)d_out;

    float* v_ws    = ws + V_OFF;
    float* attn_ws = ws + ATTN_OFF;

    // 0) reduce attention weights (4644 work items)
    reduce_weights_kernel<<<19, 256, 0, stream>>>(Wfg, bfg, Wbg, bbg, ws);

    // 1) projections: one thread per pixel
    int np = NB * HW;                      // 65536
    proj_kernel<<<np / 256, 256, 0, stream>>>(x, fg, bg, Wv, bv, ws, v_ws, attn_ws);

    // 2) aggregation: one thread per (pixel, head)
    agg_kernel<<<np * 4 / 256, 256, 0, stream>>>(v_ws, attn_ws, out);
}

// Round 2
// 56.181 us; speedup vs baseline: 1.3207x; 1.3207x over previous
//
#include <hip/hip_runtime.h>

#define HGT 128
#define WID 128
#define HW  (HGT * WID)          // 16384
#define CCH 64
#define NHEADS 4
#define NA 36                    // HEADS * KK
#define NB 4

// workspace layout (floats)
#define WR_FG_OFF 0              // 64*36
#define WR_BG_OFF 2304           // 64*36
#define BIAS_OFF  4608           // 36
#define V_OFF     4672           // B*64*HW = 4194304
#define ATTN_OFF  (4672 + 4194304)  // B*36*HW = 2359296

// ---------------------------------------------------------------------------
// Kernel 0: reduce attention weights over the summed i-axis.
// Wr[c][h*9+j] = sum_i W[c][h*81 + i*9 + j];  bias_attn[hj] = sum_i (bfg+bbg)
// ---------------------------------------------------------------------------
__global__ void reduce_weights_kernel(const float* __restrict__ Wfg,
                                      const float* __restrict__ bfg,
                                      const float* __restrict__ Wbg,
                                      const float* __restrict__ bbg,
                                      float* __restrict__ ws) {
    int idx = blockIdx.x * 256 + threadIdx.x;
    if (idx < 2 * 2304) {
        int which = idx / 2304;
        int r = idx % 2304;
        int c = r / 36, hj = r % 36;
        int h = hj / 9, j = hj % 9;
        const float* W = which ? Wbg : Wfg;
        float s = 0.f;
        #pragma unroll
        for (int i = 0; i < 9; i++) s += W[c * 324 + h * 81 + i * 9 + j];
        ws[(which ? WR_BG_OFF : WR_FG_OFF) + r] = s;
    } else if (idx < 2 * 2304 + 36) {
        int hj = idx - 4608;
        int h = hj / 9, j = hj % 9;
        float s = 0.f;
        #pragma unroll
        for (int i = 0; i < 9; i++)
            s += bfg[h * 81 + i * 9 + j] + bbg[h * 81 + i * 9 + j];
        ws[BIAS_OFF + hj] = s;
    }
}

// ---------------------------------------------------------------------------
// Kernel 1: per-pixel projections, 4 waves per pixel-group.
// Block = 256 threads = 4 waves; each block covers 64 pixels.
// Wave t computes v-outputs [t*16, t*16+16) and attn-outputs [t*9, t*9+9).
// Lane = pixel => all global loads coalesced. Weights broadcast from LDS.
// ---------------------------------------------------------------------------
__global__ __launch_bounds__(256) void proj_kernel(
        const float* __restrict__ x, const float* __restrict__ fg,
        const float* __restrict__ bg, const float* __restrict__ Wv,
        const float* __restrict__ bv, const float* __restrict__ ws,
        float* __restrict__ v_out, float* __restrict__ attn_out) {
    __shared__ float sWv[64 * 64];
    __shared__ float sWfg[64 * 36];
    __shared__ float sWbg[64 * 36];
    __shared__ float sbv[64];
    __shared__ float sba[36];

    int tid = threadIdx.x;
    for (int i = tid; i < 64 * 64; i += 256) sWv[i] = Wv[i];
    for (int i = tid; i < 64 * 36; i += 256) {
        sWfg[i] = ws[WR_FG_OFF + i];
        sWbg[i] = ws[WR_BG_OFF + i];
    }
    if (tid < 64) sbv[tid] = bv[tid];
    if (tid < 36) sba[tid] = ws[BIAS_OFF + tid];
    __syncthreads();

    int wave = tid >> 6;               // output group 0..3
    int lane = tid & 63;               // pixel within block
    int p = blockIdx.x * 64 + lane;    // global pixel 0..65535
    int b = p >> 14;
    int l = p & (HW - 1);

    float xr[64];

    // ---- v part: outputs [wave*16, wave*16+16) ----
    const float* xb = x + (size_t)b * CCH * HW + l;
    #pragma unroll
    for (int c = 0; c < 64; c++) xr[c] = xb[(size_t)c * HW];

    int o0 = wave * 16;
    float accv[16];
    #pragma unroll
    for (int o = 0; o < 16; o++) accv[o] = sbv[o0 + o];
    #pragma unroll
    for (int c = 0; c < 64; c++) {
        float xv = xr[c];
        #pragma unroll
        for (int o = 0; o < 16; o++)
            accv[o] += xv * sWv[c * 64 + o0 + o];
    }
    #pragma unroll
    for (int o = 0; o < 16; o++)
        v_out[((size_t)b * 64 + o0 + o) * HW + l] = accv[o];

    // ---- attn part: outputs [wave*9, wave*9+9) ----
    int a0 = wave * 9;
    float acca[9];
    #pragma unroll
    for (int o = 0; o < 9; o++) acca[o] = sba[a0 + o];

    const float* fb = fg + (size_t)b * CCH * HW + l;
    #pragma unroll
    for (int c = 0; c < 64; c++) xr[c] = fb[(size_t)c * HW];
    #pragma unroll
    for (int c = 0; c < 64; c++) {
        float xv = xr[c];
        #pragma unroll
        for (int o = 0; o < 9; o++) acca[o] += xv * sWfg[c * 36 + a0 + o];
    }

    const float* gb = bg + (size_t)b * CCH * HW + l;
    #pragma unroll
    for (int c = 0; c < 64; c++) xr[c] = gb[(size_t)c * HW];
    #pragma unroll
    for (int c = 0; c < 64; c++) {
        float xv = xr[c];
        #pragma unroll
        for (int o = 0; o < 9; o++) acca[o] += xv * sWbg[c * 36 + a0 + o];
    }

    #pragma unroll
    for (int o = 0; o < 9; o++)
        attn_out[((size_t)b * 36 + a0 + o) * HW + l] = acca[o];
}

// ---------------------------------------------------------------------------
// Kernel 2: aggregation.
//   out[b][c][l] = sum_j attn[b][h(c)*9+j][l] * v[b][c][nbr_j(l)]
// One thread per (pixel, head); 16 channels per thread.
// ---------------------------------------------------------------------------
__global__ __launch_bounds__(256) void agg_kernel(
        const float* __restrict__ v, const float* __restrict__ attn,
        float* __restrict__ out) {
    int idx = blockIdx.x * 256 + threadIdx.x;     // B*4*HW threads
    int l = idx & (HW - 1);
    int rest = idx >> 14;
    int b = rest >> 2;
    int h = rest & 3;
    int y = l >> 7, xx = l & 127;

    const float* ab = attn + ((size_t)b * 36 + h * 9) * HW + l;
    float w[9];
    int off[9];
    #pragma unroll
    for (int j = 0; j < 9; j++) {
        w[j] = ab[(size_t)j * HW];
        int dy = j / 3 - 1, dx = j % 3 - 1;
        int yy = y + dy, xc = xx + dx;
        bool valid = (yy >= 0) && (yy < HGT) && (xc >= 0) && (xc < WID);
        off[j] = valid ? (yy * WID + xc) : l;
        if (!valid) w[j] = 0.f;
    }

    const float* vb = v + ((size_t)b * 64 + h * 16) * HW;
    float* ob = out + ((size_t)b * 64 + h * 16) * HW + l;
    #pragma unroll 4
    for (int c2 = 0; c2 < 16; c2++) {
        const float* vc = vb + (size_t)c2 * HW;
        float acc = 0.f;
        #pragma unroll
        for (int j = 0; j < 9; j++) acc += w[j] * vc[off[j]];
        ob[(size_t)c2 * HW] = acc;
    }
}

extern "C" void kernel_launch(void* const* d_in, const int* in_sizes, int n_in,
                              void* d_out, int out_size, void* d_ws, size_t ws_size,
                              hipStream_t stream) {
    const float* x   = (const float*)d_in[0];
    const float* fg  = (const float*)d_in[1];
    const float* bg  = (const float*)d_in[2];
    const float* Wv  = (const float*)d_in[3];
    const float* bv  = (const float*)d_in[4];
    const float* Wfg = (const float*)d_in[5];
    const float* bfg = (const float*)d_in[6];
    const float* Wbg = (const float*)d_in[7];
    const float* bbg = (const float*)d_in[8];

    float* ws  = (float*)d_ws;
    float* out = (float*)d_out;

    float* v_ws    = ws + V_OFF;
    float* attn_ws = ws + ATTN_OFF;

    // 0) reduce attention weights (4644 work items)
    reduce_weights_kernel<<<19, 256, 0, stream>>>(Wfg, bfg, Wbg, bbg, ws);

    // 1) projections: 4 waves per 64-pixel group -> 1024 blocks
    int np = NB * HW;                      // 65536
    proj_kernel<<<np / 64, 256, 0, stream>>>(x, fg, bg, Wv, bv, ws, v_ws, attn_ws);

    // 2) aggregation: one thread per (pixel, head)
    agg_kernel<<<np * 4 / 256, 256, 0, stream>>>(v_ws, attn_ws, out);
}

// Round 3
// 49.510 us; speedup vs baseline: 1.4986x; 1.1348x over previous
//
#include <hip/hip_runtime.h>

#define HGT 128
#define WID 128
#define HW  (HGT * WID)          // 16384
#define CCH 64
#define NHEADS 4
#define NA 36                    // HEADS * KK
#define NB 4

// workspace layout (floats)
#define WR_FG_OFF 0              // 64*36
#define WR_BG_OFF 2304           // 64*36
#define BIAS_OFF  4608           // 36
#define V_OFF     4672           // B*64*HW = 4194304
#define ATTN_OFF  (4672 + 4194304)  // B*36*HW = 2359296

// ---------------------------------------------------------------------------
// Kernel 0: reduce attention weights over the summed i-axis.
// Wr[c][h*9+j] = sum_i W[c][h*81 + i*9 + j];  bias_attn[hj] = sum_i (bfg+bbg)
// ---------------------------------------------------------------------------
__global__ void reduce_weights_kernel(const float* __restrict__ Wfg,
                                      const float* __restrict__ bfg,
                                      const float* __restrict__ Wbg,
                                      const float* __restrict__ bbg,
                                      float* __restrict__ ws) {
    int idx = blockIdx.x * 256 + threadIdx.x;
    if (idx < 2 * 2304) {
        int which = idx / 2304;
        int r = idx % 2304;
        int c = r / 36, hj = r % 36;
        int h = hj / 9, j = hj % 9;
        const float* W = which ? Wbg : Wfg;
        float s = 0.f;
        #pragma unroll
        for (int i = 0; i < 9; i++) s += W[c * 324 + h * 81 + i * 9 + j];
        ws[(which ? WR_BG_OFF : WR_FG_OFF) + r] = s;
    } else if (idx < 2 * 2304 + 36) {
        int hj = idx - 4608;
        int h = hj / 9, j = hj % 9;
        float s = 0.f;
        #pragma unroll
        for (int i = 0; i < 9; i++)
            s += bfg[h * 81 + i * 9 + j] + bbg[h * 81 + i * 9 + j];
        ws[BIAS_OFF + hj] = s;
    }
}

// ---------------------------------------------------------------------------
// Kernel 1: per-pixel projections — scalar-pipe weights, no LDS.
// Block = 256 threads = 4 waves; block covers 128 pixels (2 per thread).
// Wave t computes v-outputs [t*16, t*16+16) and attn-outputs [t*9, t*9+9).
// Weight indices are wave-uniform (readfirstlane'd) => compiler emits s_load;
// inner loop is v_fmac_f32 with SGPR weight operand. No LDS traffic at all.
// ---------------------------------------------------------------------------
__global__ __launch_bounds__(256) void proj_kernel(
        const float* __restrict__ x, const float* __restrict__ fg,
        const float* __restrict__ bg, const float* __restrict__ Wv,
        const float* __restrict__ bv, const float* __restrict__ ws,
        float* __restrict__ v_out, float* __restrict__ attn_out) {
    int tid  = threadIdx.x;
    int wave = __builtin_amdgcn_readfirstlane(tid >> 6);
    int lane = tid & 63;

    int pbase = blockIdx.x * 128;                 // 128 pixels per block
    int b  = __builtin_amdgcn_readfirstlane(pbase >> 14);
    int l  = (pbase & (HW - 1)) + lane;           // pixel 0; pixel 1 = l+64

    const size_t binoff = (size_t)b * CCH * HW;

    // ---------------- v part: outputs [wave*16, wave*16+16) ----------------
    int o0 = wave * 16;
    const float* xb = x + binoff + l;
    float accv0[16], accv1[16];
    #pragma unroll
    for (int o = 0; o < 16; o++) {
        float bb = bv[o0 + o];
        accv0[o] = bb; accv1[o] = bb;
    }
    for (int c0 = 0; c0 < 64; c0 += 8) {
        float x0[8], x1[8];
        #pragma unroll
        for (int cc = 0; cc < 8; cc++) {
            x0[cc] = xb[(size_t)(c0 + cc) * HW];
            x1[cc] = xb[(size_t)(c0 + cc) * HW + 64];
        }
        #pragma unroll
        for (int cc = 0; cc < 8; cc++) {
            #pragma unroll
            for (int o = 0; o < 16; o++) {
                float w = Wv[(c0 + cc) * 64 + o0 + o];   // uniform -> s_load
                accv0[o] += x0[cc] * w;
                accv1[o] += x1[cc] * w;
            }
        }
    }
    float* vo = v_out + binoff + (size_t)o0 * HW + l;
    #pragma unroll
    for (int o = 0; o < 16; o++) {
        vo[(size_t)o * HW]      = accv0[o];
        vo[(size_t)o * HW + 64] = accv1[o];
    }

    // -------------- attn part: outputs [wave*9, wave*9+9) ------------------
    int a0 = wave * 9;
    const float* fb = fg + binoff + l;
    const float* gb = bg + binoff + l;
    const float* Wf = ws + WR_FG_OFF;
    const float* Wg = ws + WR_BG_OFF;

    float acca0[9], acca1[9];
    #pragma unroll
    for (int o = 0; o < 9; o++) {
        float bb = ws[BIAS_OFF + a0 + o];
        acca0[o] = bb; acca1[o] = bb;
    }
    for (int c0 = 0; c0 < 64; c0 += 8) {
        float f0[8], f1[8], g0[8], g1[8];
        #pragma unroll
        for (int cc = 0; cc < 8; cc++) {
            f0[cc] = fb[(size_t)(c0 + cc) * HW];
            f1[cc] = fb[(size_t)(c0 + cc) * HW + 64];
            g0[cc] = gb[(size_t)(c0 + cc) * HW];
            g1[cc] = gb[(size_t)(c0 + cc) * HW + 64];
        }
        #pragma unroll
        for (int cc = 0; cc < 8; cc++) {
            #pragma unroll
            for (int o = 0; o < 9; o++) {
                float wf = Wf[(c0 + cc) * 36 + a0 + o]; // uniform -> s_load
                float wg = Wg[(c0 + cc) * 36 + a0 + o]; // uniform -> s_load
                acca0[o] += f0[cc] * wf;
                acca0[o] += g0[cc] * wg;
                acca1[o] += f1[cc] * wf;
                acca1[o] += g1[cc] * wg;
            }
        }
    }
    float* ao = attn_out + (size_t)b * NA * HW + (size_t)a0 * HW + l;
    #pragma unroll
    for (int o = 0; o < 9; o++) {
        ao[(size_t)o * HW]      = acca0[o];
        ao[(size_t)o * HW + 64] = acca1[o];
    }
}

// ---------------------------------------------------------------------------
// Kernel 2: aggregation.
//   out[b][c][l] = sum_j attn[b][h(c)*9+j][l] * v[b][c][nbr_j(l)]
// One thread per (pixel, head); 16 channels per thread.
// ---------------------------------------------------------------------------
__global__ __launch_bounds__(256) void agg_kernel(
        const float* __restrict__ v, const float* __restrict__ attn,
        float* __restrict__ out) {
    int idx = blockIdx.x * 256 + threadIdx.x;     // B*4*HW threads
    int l = idx & (HW - 1);
    int rest = idx >> 14;
    int b = rest >> 2;
    int h = rest & 3;
    int y = l >> 7, xx = l & 127;

    const float* ab = attn + ((size_t)b * 36 + h * 9) * HW + l;
    float w[9];
    int off[9];
    #pragma unroll
    for (int j = 0; j < 9; j++) {
        w[j] = ab[(size_t)j * HW];
        int dy = j / 3 - 1, dx = j % 3 - 1;
        int yy = y + dy, xc = xx + dx;
        bool valid = (yy >= 0) && (yy < HGT) && (xc >= 0) && (xc < WID);
        off[j] = valid ? (yy * WID + xc) : l;
        if (!valid) w[j] = 0.f;
    }

    const float* vb = v + ((size_t)b * 64 + h * 16) * HW;
    float* ob = out + ((size_t)b * 64 + h * 16) * HW + l;
    #pragma unroll 4
    for (int c2 = 0; c2 < 16; c2++) {
        const float* vc = vb + (size_t)c2 * HW;
        float acc = 0.f;
        #pragma unroll
        for (int j = 0; j < 9; j++) acc += w[j] * vc[off[j]];
        ob[(size_t)c2 * HW] = acc;
    }
}

extern "C" void kernel_launch(void* const* d_in, const int* in_sizes, int n_in,
                              void* d_out, int out_size, void* d_ws, size_t ws_size,
                              hipStream_t stream) {
    const float* x   = (const float*)d_in[0];
    const float* fg  = (const float*)d_in[1];
    const float* bg  = (const float*)d_in[2];
    const float* Wv  = (const float*)d_in[3];
    const float* bv  = (const float*)d_in[4];
    const float* Wfg = (const float*)d_in[5];
    const float* bfg = (const float*)d_in[6];
    const float* Wbg = (const float*)d_in[7];
    const float* bbg = (const float*)d_in[8];

    float* ws  = (float*)d_ws;
    float* out = (float*)d_out;

    float* v_ws    = ws + V_OFF;
    float* attn_ws = ws + ATTN_OFF;

    // 0) reduce attention weights (4644 work items)
    reduce_weights_kernel<<<19, 256, 0, stream>>>(Wfg, bfg, Wbg, bbg, ws);

    // 1) projections: 128 pixels per block -> 512 blocks
    int np = NB * HW;                      // 65536
    proj_kernel<<<np / 128, 256, 0, stream>>>(x, fg, bg, Wv, bv, ws, v_ws, attn_ws);

    // 2) aggregation: one thread per (pixel, head)
    agg_kernel<<<np * 4 / 256, 256, 0, stream>>>(v_ws, attn_ws, out);
}